// Round 4
// baseline (1180.759 us; speedup 1.0000x reference)
//
#include <hip/hip_runtime.h>

typedef float v2f __attribute__((ext_vector_type(2)));
typedef float v4f __attribute__((ext_vector_type(4)));

#define HH 30
#define DIN 4

#if __has_builtin(__builtin_amdgcn_exp2f)
#define EXP2F(v) __builtin_amdgcn_exp2f(v)
#else
#define EXP2F(v) exp2f(v)
#endif

// Pre-scaled sigmoid: -log2e (or -2*log2e for tanh-as-sig) folded into the
// weights/bias, so sigmoid(raw) == rcp(1 + exp2(v)) directly.
__device__ __forceinline__ float sig2f(float v) {
    return __builtin_amdgcn_rcpf(1.0f + EXP2F(v));
}
__device__ __forceinline__ v2f fma2(v2f a, v2f b, v2f c) {
    return __builtin_elementwise_fma(a, b, c);
}
__device__ __forceinline__ v2f splat2(float s) { return (v2f)s; }

// DPP reduce step: x += dpp_shifted(x), OOB/masked lanes contribute 0
template <int Ctrl, int RowMask>
__device__ __forceinline__ float dpp_step(float x) {
    union { float f; int i; } in, out;
    in.f = x;
    out.i = __builtin_amdgcn_update_dpp(0, in.i, Ctrl, RowMask, 0xf, false);
    return x + out.f;
}
// Sum across each 32-lane half; lane31 = sum(lanes 0..31), lane63 = sum(32..63).
__device__ __forceinline__ float half_reduce(float x) {
    x = dpp_step<0x111, 0xf>(x);   // row_shr:1
    x = dpp_step<0x112, 0xf>(x);   // row_shr:2
    x = dpp_step<0x114, 0xf>(x);   // row_shr:4
    x = dpp_step<0x118, 0xf>(x);   // row_shr:8
    x = dpp_step<0x142, 0xa>(x);   // row_bcast:15 into rows 1,3
    return x;
}

// Broadcast each 32-lane half's value to all 64 lanes via permlane32_swap
// (single VALU instr, both outputs; no DS pipe).
__device__ __forceinline__ void bcast_halves(int ahalf, float x, float& lo, float& hi) {
#if __has_builtin(__builtin_amdgcn_permlane32_swap)
    union { float f; unsigned u; } c; c.f = x;
    auto r = __builtin_amdgcn_permlane32_swap(c.u, c.u, false, false);
    union { unsigned u; float f; } o0, o1;
    o0.u = r[0];   // {x_lo, x_lo}
    o1.u = r[1];   // {x_hi, x_hi}
    lo = o0.f;
    hi = o1.f;
#else
    const float p = __shfl_xor(x, 32, 64);
    lo = ahalf ? p : x;
    hi = ahalf ? x : p;
#endif
}

// TWO batch elements per wave (A and B), one wave per block.
// Weights are batch-invariant -> shared registers; only state duplicates.
// The two elements' FMA/activation chains are independent, interleaved at
// source level so element B's work statically fills element A's LDS
// turnaround + trans-chain latency (and vice versa). Grid = B/2 blocks ->
// 1 wave/SIMD; unified VGPR+AGPR budget ~512 regs absorbs ~290 live values.
__global__ __attribute__((amdgpu_flat_work_group_size(64, 64),
                          amdgpu_waves_per_eu(1, 1)))
void lstm2_kernel(const float* __restrict__ x,
                  const float* __restrict__ Wih1, const float* __restrict__ bih1,
                  const float* __restrict__ Whh1, const float* __restrict__ bhh1,
                  const float* __restrict__ Wih2, const float* __restrict__ bih2,
                  const float* __restrict__ Whh2, const float* __restrict__ bhh2,
                  const float* __restrict__ Wlin, const float* __restrict__ blin,
                  float* __restrict__ out, int T)
{
    const int tid = threadIdx.x;
    const int a = tid >> 5;
    const int h = tid & 31;
    const bool act = (h < HH);
    const int hc = act ? h : (HH - 1);
    const int r0 = (2 * a) * HH + hc;
    const int r1 = (2 * a + 1) * HH + hc;
    const int b0 = blockIdx.x * 2;

    __shared__ __align__(16) float shA1[32];
    __shared__ __align__(16) float shA2[32];
    __shared__ __align__(16) float shB1[32];
    __shared__ __align__(16) float shB2[32];

    // Row scale: i/f/o rows -log2e; g rows (r0 of half a=1) -2*log2e.
    const float L2E = 1.44269504088896340736f;
    const v2f sc = a ? (v2f){-2.0f * L2E, -L2E} : (v2f){-L2E, -L2E};
    const float M2 = -2.0f * L2E;          // tanh(c) = 2*rcp(1+exp2(M2*c))-1

    // ---- per-lane packed weights (pre-scaled, SHARED by both elements) ----
    v2f wx[DIN], wh1[HH], wi2[HH], wh2[HH];
#pragma unroll
    for (int c = 0; c < DIN; ++c)
        wx[c] = (v2f){Wih1[r0 * DIN + c], Wih1[r1 * DIN + c]} * sc;
#pragma unroll
    for (int k = 0; k < HH; ++k) {
        wh1[k] = (v2f){Whh1[r0 * HH + k], Whh1[r1 * HH + k]} * sc;
        wi2[k] = (v2f){Wih2[r0 * HH + k], Wih2[r1 * HH + k]} * sc;
        wh2[k] = (v2f){Whh2[r0 * HH + k], Whh2[r1 * HH + k]} * sc;
    }
    const v2f bias1 = (v2f){bih1[r0] + bhh1[r0], bih1[r1] + bhh1[r1]} * sc;
    const v2f bias2 = (v2f){bih2[r0] + bhh2[r0], bih2[r1] + bhh2[r1]} * sc;
    const v2f wlo = act ? (v2f){Wlin[(2 * a) * HH + hc], Wlin[(2 * a + 1) * HH + hc]}
                        : splat2(0.0f);
    const v2f blv = (v2f){blin[2 * a], blin[2 * a + 1]};

    const float outS = a ? 2.0f : 1.0f;
    const float outB = a ? -1.0f : 0.0f;

    float c1A = 0.0f, c2A = 0.0f, c1B = 0.0f, c2B = 0.0f;
    shA1[h] = 0.0f; shA2[h] = 0.0f; shB1[h] = 0.0f; shB2[h] = 0.0f;

    const v4f* xpA = reinterpret_cast<const v4f*>(x) + (size_t)b0 * T;
    const v4f* xpB = xpA + T;
    v2f* opA = reinterpret_cast<v2f*>(out) + (size_t)b0 * T * 2 + a;
    v2f* opB = opA + (size_t)T * 2;
    const v4f* sA1 = reinterpret_cast<const v4f*>(shA1);
    const v4f* sA2 = reinterpret_cast<const v4f*>(shA2);
    const v4f* sB1 = reinterpret_cast<const v4f*>(shB1);
    const v4f* sB2 = reinterpret_cast<const v4f*>(shB2);

    // ---- prologue: L1(0) with h1_{-1} = 0, per element ----
    {
        const v4f x0 = xpA[0];
        v2f P = bias1;
        P = fma2(wx[0], splat2(x0.x), P);
        P = fma2(wx[1], splat2(x0.y), P);
        P = fma2(wx[2], splat2(x0.z), P);
        P = fma2(wx[3], splat2(x0.w), P);
        float t0 = fmaf(outS, sig2f(P.x), outB);
        float t1 = sig2f(P.y);
        float iv, gv, fv, ov;
        bcast_halves(a, t0, iv, gv);
        bcast_halves(a, t1, fv, ov);
        (void)fv;
        c1A = iv * gv;
        shA1[h] = ov * fmaf(2.0f, sig2f(M2 * c1A), -1.0f);
    }
    {
        const v4f x0 = xpB[0];
        v2f P = bias1;
        P = fma2(wx[0], splat2(x0.x), P);
        P = fma2(wx[1], splat2(x0.y), P);
        P = fma2(wx[2], splat2(x0.z), P);
        P = fma2(wx[3], splat2(x0.w), P);
        float t0 = fmaf(outS, sig2f(P.x), outB);
        float t1 = sig2f(P.y);
        float iv, gv, fv, ov;
        bcast_halves(a, t0, iv, gv);
        bcast_halves(a, t1, fv, ov);
        (void)fv;
        c1B = iv * gv;
        shB1[h] = ov * fmaf(2.0f, sig2f(M2 * c1B), -1.0f);
    }
    v4f xcA = xpA[(T > 1) ? 1 : 0];
    v4f xcB = xpB[(T > 1) ? 1 : 0];

    // Invariant at iter t: sh*1 = h1(t), sh*2 = h2(t-1), c1 = c1(t),
    // c2 = c2(t-1), xc = x(t+1).  (Rotated loop: computes L2(t) + L1(t+1).)
    for (int t = 0; t < T; ++t) {
        const v4f xnA = xpA[(t + 2 < T) ? (t + 2) : (T - 1)];
        const v4f xnB = xpB[(t + 2 < T) ? (t + 2) : (T - 1)];

        // Per elem: A0/A1 = Whh1@h1 + Wih1@x(t+1) + bias1 (L1, split 2 ways)
        //           Bi    = Wih2@h1 + bias2               (L2 input path)
        //           Bh    = Whh2@h2                        (L2 recurrent path)
        v2f A0A = bias1, A1A = splat2(0.0f), BiA = bias2, BhA = splat2(0.0f);
        v2f A0B = bias1, A1B = splat2(0.0f), BiB = bias2, BhB = splat2(0.0f);

        A0A = fma2(wx[0], splat2(xcA.x), A0A);
        A0B = fma2(wx[0], splat2(xcB.x), A0B);
        A0A = fma2(wx[1], splat2(xcA.y), A0A);
        A0B = fma2(wx[1], splat2(xcB.y), A0B);
        A0A = fma2(wx[2], splat2(xcA.z), A0A);
        A0B = fma2(wx[2], splat2(xcB.z), A0B);
        A0A = fma2(wx[3], splat2(xcA.w), A0A);
        A0B = fma2(wx[3], splat2(xcB.w), A0B);

#pragma unroll
        for (int j = 0; j < 7; ++j) {
            const v4f uA = sA1[j];
            const v4f vA = sA2[j];
            const v4f uB = sB1[j];
            const v4f vB = sB2[j];
            if (j & 1) {
                A1A = fma2(wh1[4 * j + 0], splat2(uA.x), A1A);
                A1B = fma2(wh1[4 * j + 0], splat2(uB.x), A1B);
                A1A = fma2(wh1[4 * j + 1], splat2(uA.y), A1A);
                A1B = fma2(wh1[4 * j + 1], splat2(uB.y), A1B);
                A1A = fma2(wh1[4 * j + 2], splat2(uA.z), A1A);
                A1B = fma2(wh1[4 * j + 2], splat2(uB.z), A1B);
                A1A = fma2(wh1[4 * j + 3], splat2(uA.w), A1A);
                A1B = fma2(wh1[4 * j + 3], splat2(uB.w), A1B);
            } else {
                A0A = fma2(wh1[4 * j + 0], splat2(uA.x), A0A);
                A0B = fma2(wh1[4 * j + 0], splat2(uB.x), A0B);
                A0A = fma2(wh1[4 * j + 1], splat2(uA.y), A0A);
                A0B = fma2(wh1[4 * j + 1], splat2(uB.y), A0B);
                A0A = fma2(wh1[4 * j + 2], splat2(uA.z), A0A);
                A0B = fma2(wh1[4 * j + 2], splat2(uB.z), A0B);
                A0A = fma2(wh1[4 * j + 3], splat2(uA.w), A0A);
                A0B = fma2(wh1[4 * j + 3], splat2(uB.w), A0B);
            }
            BiA = fma2(wi2[4 * j + 0], splat2(uA.x), BiA);
            BiB = fma2(wi2[4 * j + 0], splat2(uB.x), BiB);
            BiA = fma2(wi2[4 * j + 1], splat2(uA.y), BiA);
            BiB = fma2(wi2[4 * j + 1], splat2(uB.y), BiB);
            BiA = fma2(wi2[4 * j + 2], splat2(uA.z), BiA);
            BiB = fma2(wi2[4 * j + 2], splat2(uB.z), BiB);
            BiA = fma2(wi2[4 * j + 3], splat2(uA.w), BiA);
            BiB = fma2(wi2[4 * j + 3], splat2(uB.w), BiB);
            BhA = fma2(wh2[4 * j + 0], splat2(vA.x), BhA);
            BhB = fma2(wh2[4 * j + 0], splat2(vB.x), BhB);
            BhA = fma2(wh2[4 * j + 1], splat2(vA.y), BhA);
            BhB = fma2(wh2[4 * j + 1], splat2(vB.y), BhB);
            BhA = fma2(wh2[4 * j + 2], splat2(vA.z), BhA);
            BhB = fma2(wh2[4 * j + 2], splat2(vB.z), BhB);
            BhA = fma2(wh2[4 * j + 3], splat2(vA.w), BhA);
            BhB = fma2(wh2[4 * j + 3], splat2(vB.w), BhB);
        }
        {
            const v4f uA = sA1[7];           // only elements 28,29 live
            const v4f vA = sA2[7];
            const v4f uB = sB1[7];
            const v4f vB = sB2[7];
            A1A = fma2(wh1[28], splat2(uA.x), A1A);
            A1B = fma2(wh1[28], splat2(uB.x), A1B);
            A1A = fma2(wh1[29], splat2(uA.y), A1A);
            A1B = fma2(wh1[29], splat2(uB.y), A1B);
            BiA = fma2(wi2[28], splat2(uA.x), BiA);
            BiB = fma2(wi2[28], splat2(uB.x), BiB);
            BiA = fma2(wi2[29], splat2(uA.y), BiA);
            BiB = fma2(wi2[29], splat2(uB.y), BiB);
            BhA = fma2(wh2[28], splat2(vA.x), BhA);
            BhB = fma2(wh2[28], splat2(vB.x), BhB);
            BhA = fma2(wh2[29], splat2(vA.y), BhA);
            BhB = fma2(wh2[29], splat2(vB.y), BhB);
        }

        // ===== activation tails: 4 independent chains (2 layers x 2 elems) =====
        const v2f BvA = BiA + BhA;
        const v2f AvA = A0A + A1A;
        const v2f BvB = BiB + BhB;
        const v2f AvB = A0B + A1B;

        float q2A0 = fmaf(outS, sig2f(BvA.x), outB);     // L2 A: i/g
        float q2B0 = fmaf(outS, sig2f(BvB.x), outB);
        float q2A1 = sig2f(BvA.y);                       // L2 A: f/o
        float q2B1 = sig2f(BvB.y);
        float q1A0 = fmaf(outS, sig2f(AvA.x), outB);     // L1(t+1) A: i/g
        float q1B0 = fmaf(outS, sig2f(AvB.x), outB);
        float q1A1 = sig2f(AvA.y);                       // L1(t+1) A: f/o
        float q1B1 = sig2f(AvB.y);

        float iv2A, gv2A, fv2A, ov2A, iv1A, gv1A, fv1A, ov1A;
        float iv2B, gv2B, fv2B, ov2B, iv1B, gv1B, fv1B, ov1B;
        bcast_halves(a, q2A0, iv2A, gv2A);
        bcast_halves(a, q2B0, iv2B, gv2B);
        bcast_halves(a, q2A1, fv2A, ov2A);
        bcast_halves(a, q2B1, fv2B, ov2B);
        bcast_halves(a, q1A0, iv1A, gv1A);
        bcast_halves(a, q1B0, iv1B, gv1B);
        bcast_halves(a, q1A1, fv1A, ov1A);
        bcast_halves(a, q1B1, fv1B, ov1B);

        c2A = fmaf(fv2A, c2A, iv2A * gv2A);
        c2B = fmaf(fv2B, c2B, iv2B * gv2B);
        c1A = fmaf(fv1A, c1A, iv1A * gv1A);
        c1B = fmaf(fv1B, c1B, iv1B * gv1B);
        const float h2nA = ov2A * fmaf(2.0f, sig2f(M2 * c2A), -1.0f);  // h2(t)
        const float h2nB = ov2B * fmaf(2.0f, sig2f(M2 * c2B), -1.0f);
        const float h1nA = ov1A * fmaf(2.0f, sig2f(M2 * c1A), -1.0f);  // h1(t+1)
        const float h1nB = ov1B * fmaf(2.0f, sig2f(M2 * c1B), -1.0f);
        shA2[h] = h2nA;
        shB2[h] = h2nB;
        shA1[h] = h1nA;
        shB1[h] = h1nB;

        // ===== heads: out(t) = Wlin @ h2(t) + b — VALU-pipe DPP reduce =====
        const v2f pvA = wlo * splat2(h2nA);              // 0 on pad lanes
        const v2f pvB = wlo * splat2(h2nB);
        const float rxA = half_reduce(pvA.x);
        const float rxB = half_reduce(pvB.x);
        const float ryA = half_reduce(pvA.y);
        const float ryB = half_reduce(pvB.y);
        if ((tid & 31) == 31) {                          // lane31 (a=0), lane63 (a=1)
            opA[2 * t] = (v2f){rxA + blv.x, ryA + blv.y};
            opB[2 * t] = (v2f){rxB + blv.x, ryB + blv.y};
        }
        xcA = xnA;
        xcB = xnB;
    }
}

extern "C" void kernel_launch(void* const* d_in, const int* in_sizes, int n_in,
                              void* d_out, int out_size, void* d_ws, size_t ws_size,
                              hipStream_t stream)
{
    const float* x    = (const float*)d_in[0];
    const float* Wih1 = (const float*)d_in[1];
    const float* bih1 = (const float*)d_in[2];
    const float* Whh1 = (const float*)d_in[3];
    const float* bhh1 = (const float*)d_in[4];
    const float* Wih2 = (const float*)d_in[5];
    const float* bih2 = (const float*)d_in[6];
    const float* Whh2 = (const float*)d_in[7];
    const float* bhh2 = (const float*)d_in[8];
    const float* Wlin = (const float*)d_in[9];
    const float* blin = (const float*)d_in[10];
    float* out = (float*)d_out;

    const int T = 1024;
    const int B = in_sizes[0] / (T * DIN);   // 2048

    hipLaunchKernelGGL(lstm2_kernel, dim3(B / 2), dim3(64), 0, stream,
                       x, Wih1, bih1, Whh1, bhh1, Wih2, bih2, Whh2, bhh2,
                       Wlin, blin, out, T);
}

// Round 5
// 1106.359 us; speedup vs baseline: 1.0672x; 1.0672x over previous
//
#include <hip/hip_runtime.h>

typedef float v2f __attribute__((ext_vector_type(2)));
typedef float v4f __attribute__((ext_vector_type(4)));

#define HH 30
#define DIN 4

#if __has_builtin(__builtin_amdgcn_exp2f)
#define EXP2F(v) __builtin_amdgcn_exp2f(v)
#else
#define EXP2F(v) exp2f(v)
#endif

// Pre-scaled sigmoid: -log2e (or -2*log2e for tanh-as-sig) folded into the
// weights/bias, so sigmoid(raw) == rcp(1 + exp2(v)) directly.
__device__ __forceinline__ float sig2f(float v) {
    return __builtin_amdgcn_rcpf(1.0f + EXP2F(v));
}

// DPP reduce step: x += dpp_shifted(x), OOB/masked lanes contribute 0
template <int Ctrl, int RowMask>
__device__ __forceinline__ float dpp_step(float x) {
    union { float f; int i; } in, out;
    in.f = x;
    out.i = __builtin_amdgcn_update_dpp(0, in.i, Ctrl, RowMask, 0xf, false);
    return x + out.f;
}
// Sum across each 32-lane half; lane31 = sum(lanes 0..31), lane63 = sum(32..63).
__device__ __forceinline__ float half_reduce(float x) {
    x = dpp_step<0x111, 0xf>(x);   // row_shr:1
    x = dpp_step<0x112, 0xf>(x);   // row_shr:2
    x = dpp_step<0x114, 0xf>(x);   // row_shr:4
    x = dpp_step<0x118, 0xf>(x);   // row_shr:8
    x = dpp_step<0x142, 0xa>(x);   // row_bcast:15 into rows 1,3
    return x;
}

// Broadcast each 32-lane half's value to all 64 lanes via permlane32_swap
// (single VALU instr, both outputs; no DS pipe).
__device__ __forceinline__ void bcast_halves(int ahalf, float x, float& lo, float& hi) {
#if __has_builtin(__builtin_amdgcn_permlane32_swap)
    union { float f; unsigned u; } c; c.f = x;
    auto r = __builtin_amdgcn_permlane32_swap(c.u, c.u, false, false);
    union { unsigned u; float f; } o0, o1;
    o0.u = r[0];   // {x_lo, x_lo}
    o1.u = r[1];   // {x_hi, x_hi}
    lo = o0.f;
    hi = o1.f;
#else
    const float p = __shfl_xor(x, 32, 64);
    lo = ahalf ? p : x;
    hi = ahalf ? x : p;
#endif
}

// One wave per block, one batch element per wave (R3 structure — best so far).
// a = lane>>5: a=0 owns (i,f) gate rows, a=1 owns (g,o) rows; h = lane&31.
//
// THIS ROUND: scalar v_fma_f32 instead of v_pk_fma_f32. The LDS read of h
// already broadcasts (all lanes read the same 16B), so u.x is lane-uniform
// and feeds v_fma_f32 directly as an operand. The packed form required
// materializing {u.x,u.x} 64-bit pairs (~2 v_mov per unique value, ~128
// movs/step) because HIP can't express VOP3P op_sel broadcast. Scalar FMA is
// full-rate (m07), so FMA occupancy is unchanged while the mov bloat dies.
// Six accumulator chains (2 rows x {L1, L2-in, L2-rec}), depth <=34.
__global__ __attribute__((amdgpu_flat_work_group_size(64, 64),
                          amdgpu_waves_per_eu(2, 2)))
void lstm2_kernel(const float* __restrict__ x,
                  const float* __restrict__ Wih1, const float* __restrict__ bih1,
                  const float* __restrict__ Whh1, const float* __restrict__ bhh1,
                  const float* __restrict__ Wih2, const float* __restrict__ bih2,
                  const float* __restrict__ Whh2, const float* __restrict__ bhh2,
                  const float* __restrict__ Wlin, const float* __restrict__ blin,
                  float* __restrict__ out, int T)
{
    const int tid = threadIdx.x;
    const int a = tid >> 5;
    const int h = tid & 31;
    const bool act = (h < HH);
    const int hc = act ? h : (HH - 1);
    const int r0 = (2 * a) * HH + hc;        // i (a=0) / g (a=1) row
    const int r1 = (2 * a + 1) * HH + hc;    // f (a=0) / o (a=1) row
    const int b = blockIdx.x;

    __shared__ __align__(16) float sh1[32];
    __shared__ __align__(16) float sh2[32];

    // Row scale: i/f/o rows -log2e; g rows (r0 of half a=1) -2*log2e.
    const float L2E = 1.44269504088896340736f;
    const float sc0 = a ? -2.0f * L2E : -L2E;
    const float sc1 = -L2E;
    const float M2 = -2.0f * L2E;            // tanh(c) = 2*rcp(1+exp2(M2*c))-1

    // ---- per-lane scalar weights (pre-scaled) ----
    float wx0[DIN], wx1[DIN];
    float wh1a[HH], wh1b[HH], wi2a[HH], wi2b[HH], wh2a[HH], wh2b[HH];
#pragma unroll
    for (int c = 0; c < DIN; ++c) {
        wx0[c] = Wih1[r0 * DIN + c] * sc0;
        wx1[c] = Wih1[r1 * DIN + c] * sc1;
    }
#pragma unroll
    for (int k = 0; k < HH; ++k) {
        wh1a[k] = Whh1[r0 * HH + k] * sc0;
        wh1b[k] = Whh1[r1 * HH + k] * sc1;
        wi2a[k] = Wih2[r0 * HH + k] * sc0;
        wi2b[k] = Wih2[r1 * HH + k] * sc1;
        wh2a[k] = Whh2[r0 * HH + k] * sc0;
        wh2b[k] = Whh2[r1 * HH + k] * sc1;
    }
    const float bias1_0 = (bih1[r0] + bhh1[r0]) * sc0;
    const float bias1_1 = (bih1[r1] + bhh1[r1]) * sc1;
    const float bias2_0 = (bih2[r0] + bhh2[r0]) * sc0;
    const float bias2_1 = (bih2[r1] + bhh2[r1]) * sc1;
    const float wl0 = act ? Wlin[(2 * a) * HH + hc] : 0.0f;     // 0 on pad lanes
    const float wl1 = act ? Wlin[(2 * a + 1) * HH + hc] : 0.0f;
    const float bl0 = blin[2 * a];
    const float bl1 = blin[2 * a + 1];

    const float outS = a ? 2.0f : 1.0f;
    const float outB = a ? -1.0f : 0.0f;

    float c1 = 0.0f, c2 = 0.0f;
    sh1[h] = 0.0f;
    sh2[h] = 0.0f;

    const v4f* xp = reinterpret_cast<const v4f*>(x) + (size_t)b * T;
    v2f* op = reinterpret_cast<v2f*>(out) + (size_t)b * T * 2 + a;
    const v4f* s1v = reinterpret_cast<const v4f*>(sh1);
    const v4f* s2v = reinterpret_cast<const v4f*>(sh2);

    // ---- phase stagger: de-phase co-resident waves (numeric no-op) ----
    {
        const int phase = b & 3;
#pragma unroll 1
        for (int i = 0; i < phase; ++i)
            __builtin_amdgcn_s_sleep(7);   // ~448 cyc each
    }

    // ---- prologue: L1(0) with h1_{-1} = 0 (no Whh1 terms) ----
    {
        const v4f x0 = xp[0];
        float P0 = bias1_0, P1 = bias1_1;
        P0 = fmaf(wx0[0], x0.x, P0); P1 = fmaf(wx1[0], x0.x, P1);
        P0 = fmaf(wx0[1], x0.y, P0); P1 = fmaf(wx1[1], x0.y, P1);
        P0 = fmaf(wx0[2], x0.z, P0); P1 = fmaf(wx1[2], x0.z, P1);
        P0 = fmaf(wx0[3], x0.w, P0); P1 = fmaf(wx1[3], x0.w, P1);
        float t0 = fmaf(outS, sig2f(P0), outB);
        float t1 = sig2f(P1);
        float iv, gv, fv, ov;
        bcast_halves(a, t0, iv, gv);
        bcast_halves(a, t1, fv, ov);
        (void)fv;
        c1 = iv * gv;
        sh1[h] = ov * fmaf(2.0f, sig2f(M2 * c1), -1.0f);   // h1(0)
    }
    v4f xc = xp[(T > 1) ? 1 : 0];                          // x(1)

    // Invariant at iter t: sh1 = h1(t), sh2 = h2(t-1), c1 = c1(t),
    // c2 = c2(t-1), xc = x(t+1).  (Rotated loop: computes L2(t) + L1(t+1).)
    for (int t = 0; t < T; ++t) {
        const v4f xn = xp[(t + 2 < T) ? (t + 2) : (T - 1)];

        // ===== 6 independent scalar FMA chains =====
        // A0/A1 : Whh1@h1 + Wih1@x(t+1) + bias1   (L1 for t+1, rows r0/r1)
        // Bi0/1 : Wih2@h1 + bias2                 (L2 input path)
        // Bh0/1 : Whh2@h2                         (L2 recurrent path)
        float A0 = bias1_0, A1 = bias1_1;
        float Bi0 = bias2_0, Bi1 = bias2_1;
        float Bh0 = 0.0f, Bh1 = 0.0f;

        A0 = fmaf(wx0[0], xc.x, A0); A1 = fmaf(wx1[0], xc.x, A1);
        A0 = fmaf(wx0[1], xc.y, A0); A1 = fmaf(wx1[1], xc.y, A1);
        A0 = fmaf(wx0[2], xc.z, A0); A1 = fmaf(wx1[2], xc.z, A1);
        A0 = fmaf(wx0[3], xc.w, A0); A1 = fmaf(wx1[3], xc.w, A1);

#pragma unroll
        for (int j = 0; j < 8; ++j) {
            const v4f u = s1v[j];            // h1(t): lane-uniform broadcast
            const v4f v = s2v[j];            // h2(t-1)
#pragma unroll
            for (int e = 0; e < 4; ++e) {
                const int k = 4 * j + e;
                if (k < HH) {
                    const float ue = u[e];
                    const float ve = v[e];
                    A0  = fmaf(wh1a[k], ue, A0);
                    A1  = fmaf(wh1b[k], ue, A1);
                    Bi0 = fmaf(wi2a[k], ue, Bi0);
                    Bi1 = fmaf(wi2b[k], ue, Bi1);
                    Bh0 = fmaf(wh2a[k], ve, Bh0);
                    Bh1 = fmaf(wh2b[k], ve, Bh1);
                }
            }
        }

        // ===== two independent activation/update tails =====
        const float Bv0 = Bi0 + Bh0;
        const float Bv1 = Bi1 + Bh1;

        float b0 = fmaf(outS, sig2f(Bv0), outB);   // L2: i/g
        float b1 = sig2f(Bv1);                     // L2: f/o
        float a0v = fmaf(outS, sig2f(A0), outB);   // L1(t+1): i/g
        float a1v = sig2f(A1);                     // L1(t+1): f/o

        float iv2, gv2, fv2, ov2, iv1, gv1, fv1, ov1;
        bcast_halves(a, b0, iv2, gv2);
        bcast_halves(a, b1, fv2, ov2);
        bcast_halves(a, a0v, iv1, gv1);
        bcast_halves(a, a1v, fv1, ov1);

        c2 = fmaf(fv2, c2, iv2 * gv2);
        c1 = fmaf(fv1, c1, iv1 * gv1);
        const float h2n = ov2 * fmaf(2.0f, sig2f(M2 * c2), -1.0f);  // h2(t)
        const float h1n = ov1 * fmaf(2.0f, sig2f(M2 * c1), -1.0f);  // h1(t+1)
        sh2[h] = h2n;
        sh1[h] = h1n;

        // ===== head: out(t) = Wlin @ h2(t) + b — VALU-pipe DPP reduce =====
        const float rx = half_reduce(wl0 * h2n);   // 0 on pad lanes
        const float ry = half_reduce(wl1 * h2n);
        if ((tid & 31) == 31) {                    // lane31 (a=0), lane63 (a=1)
            op[2 * t] = (v2f){rx + bl0, ry + bl1};
        }
        xc = xn;
    }
}

extern "C" void kernel_launch(void* const* d_in, const int* in_sizes, int n_in,
                              void* d_out, int out_size, void* d_ws, size_t ws_size,
                              hipStream_t stream)
{
    const float* x    = (const float*)d_in[0];
    const float* Wih1 = (const float*)d_in[1];
    const float* bih1 = (const float*)d_in[2];
    const float* Whh1 = (const float*)d_in[3];
    const float* bhh1 = (const float*)d_in[4];
    const float* Wih2 = (const float*)d_in[5];
    const float* bih2 = (const float*)d_in[6];
    const float* Whh2 = (const float*)d_in[7];
    const float* bhh2 = (const float*)d_in[8];
    const float* Wlin = (const float*)d_in[9];
    const float* blin = (const float*)d_in[10];
    float* out = (float*)d_out;

    const int T = 1024;
    const int B = in_sizes[0] / (T * DIN);   // 2048

    hipLaunchKernelGGL(lstm2_kernel, dim3(B), dim3(64), 0, stream,
                       x, Wih1, bih1, Whh1, bhh1, Wih2, bih2, Whh2, bhh2,
                       Wlin, blin, out, T);
}